// Round 4
// baseline (192.012 us; speedup 1.0000x reference)
//
#include <hip/hip_runtime.h>
#include <math.h>

#define NS    512
#define NOBJ  16
#define MPTS  8192
#define HH    128
#define WW    128
#define HW    (HH * WW)
#define BLOCK 256
#define SPLIT 4                 // blocks per sample
#define NWAVE (BLOCK / 64)

__device__ __forceinline__ float frcp(float x)  { return __builtin_amdgcn_rcpf(x); }
__device__ __forceinline__ float fsqrt(float x) { return __builtin_amdgcn_sqrtf(x); }
// Force a wave-uniform float into an SGPR (value identical across lanes).
__device__ __forceinline__ float rfl(float x) {
    return __int_as_float(__builtin_amdgcn_readfirstlane(__float_as_int(x)));
}

// ---------------- kernel A: partial sums per (sample, chunk) ----------------
__global__ __launch_bounds__(BLOCK) void score_partial(
    const int*   __restrict__ obj_id,     // [N]
    const float* __restrict__ cam_K,      // [N,3,3]
    const float* __restrict__ gt_R,       // [N,3,3]
    const float* __restrict__ gt_t,       // [N,3]
    const float* __restrict__ pr_R,       // [N,3,3]
    const float* __restrict__ pr_t,       // [N,3]
    const float* __restrict__ coord,      // [N,3,H,W]
    const int*   __restrict__ mask,       // [N,1,H,W]
    const float* __restrict__ mesh,       // [NOBJ,M,3]
    float*       __restrict__ ws,         // [N,SPLIT,4] partials: ad,pj,pv,m
    float*       __restrict__ out)        // [5*N]; this kernel writes re,te
{
    const int b   = blockIdx.x;
    const int n   = b >> 2;               // sample
    const int c   = b & (SPLIT - 1);      // chunk
    const int tid = threadIdx.x;

    // ---- per-sample uniforms ----
    float K[9], Rg[9], Rp[9], tg[3], tp[3];
#pragma unroll
    for (int i = 0; i < 9; ++i) {
        K[i]  = cam_K[n * 9 + i];
        Rg[i] = gt_R [n * 9 + i];
        Rp[i] = pr_R [n * 9 + i];
    }
#pragma unroll
    for (int i = 0; i < 3; ++i) {
        tg[i] = gt_t[n * 3 + i];
        tp[i] = pr_t[n * 3 + i];
    }
    const int obj = __builtin_amdgcn_readfirstlane(obj_id[n]);

    // re/te once per sample (chunk 0 only)
    if (c == 0 && tid == 0) {
        float trace = 0.0f;
#pragma unroll
        for (int i = 0; i < 9; ++i) trace += Rp[i] * Rg[i];
        trace = fminf(fmaxf(trace, -1.0f), 3.0f);
        out[0 * NS + n] = acosf((trace - 1.0f) * 0.5f) * (180.0f / 3.14159265358979323846f);
        const float dx = tp[0] - tg[0], dy = tp[1] - tg[1], dz = tp[2] - tg[2];
        out[1 * NS + n] = sqrtf(dx * dx + dy * dy + dz * dz) * 100.0f;
    }

    // ---- fused constants -> SGPRs via readfirstlane ----
    float dR[9], dt[3], Ap[9], Ag[9], bp[3], bg[3];
#pragma unroll
    for (int i = 0; i < 9; ++i) dR[i] = rfl(Rp[i] - Rg[i]);
#pragma unroll
    for (int i = 0; i < 3; ++i) dt[i] = rfl(tp[i] - tg[i]);
#pragma unroll
    for (int r = 0; r < 3; ++r) {
#pragma unroll
        for (int col = 0; col < 3; ++col) {
            Ap[r * 3 + col] = rfl(K[r * 3 + 0] * Rp[0 * 3 + col]
                                + K[r * 3 + 1] * Rp[1 * 3 + col]
                                + K[r * 3 + 2] * Rp[2 * 3 + col]);
            Ag[r * 3 + col] = rfl(K[r * 3 + 0] * Rg[0 * 3 + col]
                                + K[r * 3 + 1] * Rg[1 * 3 + col]
                                + K[r * 3 + 2] * Rg[2 * 3 + col]);
        }
        bp[r] = rfl(K[r * 3 + 0] * tp[0] + K[r * 3 + 1] * tp[1] + K[r * 3 + 2] * tp[2]);
        bg[r] = rfl(K[r * 3 + 0] * tg[0] + K[r * 3 + 1] * tg[1] + K[r * 3 + 2] * tg[2]);
    }

    float s_ad = 0.0f, s_pj = 0.0f;

    // ---- phase 1: mesh chunk (MPTS/SPLIT points), 4 pts/thread/iter ----
    const float4* mp4 = (const float4*)(mesh + (size_t)obj * MPTS * 3);
#pragma unroll
    for (int it = 0; it < MPTS / SPLIT / (BLOCK * 4); ++it) {
        const int k = c * (MPTS / SPLIT / 4) + it * BLOCK + tid;
        const float4 f0 = mp4[k * 3 + 0];
        const float4 f1 = mp4[k * 3 + 1];
        const float4 f2 = mp4[k * 3 + 2];
        const float px[4] = {f0.x, f0.w, f1.z, f2.y};
        const float py[4] = {f0.y, f1.x, f1.w, f2.z};
        const float pz[4] = {f0.z, f1.y, f2.x, f2.w};
#pragma unroll
        for (int j = 0; j < 4; ++j) {
            const float x = px[j], y = py[j], z = pz[j];
            const float dx = fmaf(dR[0], x, fmaf(dR[1], y, fmaf(dR[2], z, dt[0])));
            const float dy = fmaf(dR[3], x, fmaf(dR[4], y, fmaf(dR[5], z, dt[1])));
            const float dz = fmaf(dR[6], x, fmaf(dR[7], y, fmaf(dR[8], z, dt[2])));
            s_ad += fsqrt(fmaf(dx, dx, fmaf(dy, dy, dz * dz)));
            const float hpx = fmaf(Ap[0], x, fmaf(Ap[1], y, fmaf(Ap[2], z, bp[0])));
            const float hpy = fmaf(Ap[3], x, fmaf(Ap[4], y, fmaf(Ap[5], z, bp[1])));
            const float hpz = fmaf(Ap[6], x, fmaf(Ap[7], y, fmaf(Ap[8], z, bp[2])));
            const float hgx = fmaf(Ag[0], x, fmaf(Ag[1], y, fmaf(Ag[2], z, bg[0])));
            const float hgy = fmaf(Ag[3], x, fmaf(Ag[4], y, fmaf(Ag[5], z, bg[1])));
            const float hgz = fmaf(Ag[6], x, fmaf(Ag[7], y, fmaf(Ag[8], z, bg[2])));
            const float iwp = frcp(hpz), iwg = frcp(hgz);
            const float du = fmaf(hpx, iwp, -hgx * iwg);
            const float dv = fmaf(hpy, iwp, -hgy * iwg);
            s_pj += fsqrt(fmaf(du, du, dv * dv));
        }
    }

    // ---- phase 2: pixel chunk (HW/SPLIT pixels), float4 vectorized ----
    const float* cx = coord + (size_t)n * 3 * HW;
    const float4* cx4 = (const float4*)cx;
    const float4* cy4 = (const float4*)(cx + HW);
    const float4* cz4 = (const float4*)(cx + 2 * HW);
    const int4*   mk4 = (const int4*)(mask + (size_t)n * HW);

    float s_pv = 0.0f, s_m = 0.0f;
#pragma unroll
    for (int it = 0; it < HW / 4 / SPLIT / BLOCK; ++it) {
        const int p = c * (HW / 4 / SPLIT) + it * BLOCK + tid;
        const float4 vx = cx4[p];
        const float4 vy = cy4[p];
        const float4 vz = cz4[p];
        const int4   mm = mk4[p];
        const float xs[4] = {vx.x, vx.y, vx.z, vx.w};
        const float ys[4] = {vy.x, vy.y, vy.z, vy.w};
        const float zs[4] = {vz.x, vz.y, vz.z, vz.w};
        const int   ms[4] = {mm.x, mm.y, mm.z, mm.w};
#pragma unroll
        for (int j = 0; j < 4; ++j) {
            const float x = xs[j], y = ys[j], z = zs[j];
            const float hpx = fmaf(Ap[0], x, fmaf(Ap[1], y, fmaf(Ap[2], z, bp[0])));
            const float hpy = fmaf(Ap[3], x, fmaf(Ap[4], y, fmaf(Ap[5], z, bp[1])));
            const float hpz = fmaf(Ap[6], x, fmaf(Ap[7], y, fmaf(Ap[8], z, bp[2])));
            const float hgx = fmaf(Ag[0], x, fmaf(Ag[1], y, fmaf(Ag[2], z, bg[0])));
            const float hgy = fmaf(Ag[3], x, fmaf(Ag[4], y, fmaf(Ag[5], z, bg[1])));
            const float hgz = fmaf(Ag[6], x, fmaf(Ag[7], y, fmaf(Ag[8], z, bg[2])));
            const float iwp = frcp(hpz), iwg = frcp(hgz);
            const float du = fmaf(hpx, iwp, -hgx * iwg);
            const float dv = fmaf(hpy, iwp, -hgy * iwg);
            const float d  = fsqrt(fmaf(du, du, dv * dv));
            const float fm = (ms[j] != 0) ? 1.0f : 0.0f;
            s_pv += d * fm;
            s_m  += fm;
        }
    }

    // ---- block reduction of 4 sums ----
    float vals[4] = {s_ad, s_pj, s_pv, s_m};
#pragma unroll
    for (int k = 0; k < 4; ++k) {
#pragma unroll
        for (int off = 32; off > 0; off >>= 1)
            vals[k] += __shfl_down(vals[k], off, 64);
    }
    __shared__ float red[4][NWAVE];
    const int wave = tid >> 6;
    const int lane = tid & 63;
    if (lane == 0) {
#pragma unroll
        for (int k = 0; k < 4; ++k) red[k][wave] = vals[k];
    }
    __syncthreads();
    if (tid == 0) {
#pragma unroll
        for (int k = 0; k < 4; ++k) {
            float s = 0.0f;
#pragma unroll
            for (int w = 0; w < NWAVE; ++w) s += red[k][w];
            ws[(size_t)(n * SPLIT + c) * 4 + k] = s;
        }
    }
}

// ---------------- kernel B: final reduce over chunks ----------------
__global__ __launch_bounds__(256) void score_reduce(
    const float* __restrict__ ws,        // [N,SPLIT,4]
    const int*   __restrict__ obj_id,    // [N]
    const float* __restrict__ diam,      // [NOBJ]
    float*       __restrict__ out)       // [5*N]
{
    const int n = blockIdx.x * blockDim.x + threadIdx.x;
    if (n >= NS) return;
    float ad = 0.0f, pj = 0.0f, pv = 0.0f, m = 0.0f;
#pragma unroll
    for (int cb = 0; cb < SPLIT; ++cb) {
        const float* p = ws + (size_t)(n * SPLIT + cb) * 4;
        ad += p[0]; pj += p[1]; pv += p[2]; m += p[3];
    }
    const float dia = diam[obj_id[n]];
    out[2 * NS + n] = ad * (1.0f / MPTS) / dia;
    out[3 * NS + n] = pj * (1.0f / MPTS);
    out[4 * NS + n] = pv / fmaxf(m, 1.0f);
}

extern "C" void kernel_launch(void* const* d_in, const int* in_sizes, int n_in,
                              void* d_out, int out_size, void* d_ws, size_t ws_size,
                              hipStream_t stream) {
    const int*   obj_id = (const int*)  d_in[0];
    const float* cam_K  = (const float*)d_in[1];
    const float* gt_R   = (const float*)d_in[2];
    const float* gt_t   = (const float*)d_in[3];
    const float* pr_R   = (const float*)d_in[4];
    const float* pr_t   = (const float*)d_in[5];
    const float* coord  = (const float*)d_in[6];
    const int*   mask   = (const int*)  d_in[7];
    const float* mesh   = (const float*)d_in[8];
    const float* diam   = (const float*)d_in[9];
    float* out = (float*)d_out;
    float* ws  = (float*)d_ws;   // needs N*SPLIT*4*4 = 32 KB

    score_partial<<<NS * SPLIT, BLOCK, 0, stream>>>(obj_id, cam_K, gt_R, gt_t, pr_R,
                                                    pr_t, coord, mask, mesh, ws, out);
    score_reduce<<<(NS + 255) / 256, 256, 0, stream>>>(ws, obj_id, diam, out);
}

// Round 5
// 189.785 us; speedup vs baseline: 1.0117x; 1.0117x over previous
//
#include <hip/hip_runtime.h>
#include <math.h>

#define NS    512
#define NOBJ  16
#define MPTS  8192
#define HH    128
#define WW    128
#define HW    (HH * WW)
#define BLOCK 256
#define SPLIT 4                 // blocks per sample
#define NWAVE (BLOCK / 64)
#define P2_IT (HW / 4 / SPLIT / BLOCK)      // 4 phase-2 iters per thread
#define P1_IT (MPTS / SPLIT / (BLOCK * 4))  // 2 phase-1 iters per thread

__device__ __forceinline__ float frcp(float x)  { return __builtin_amdgcn_rcpf(x); }
__device__ __forceinline__ float fsqrt(float x) { return __builtin_amdgcn_sqrtf(x); }
// Force a wave-uniform float into an SGPR.
__device__ __forceinline__ float rfl(float x) {
    return __int_as_float(__builtin_amdgcn_readfirstlane(__float_as_int(x)));
}

// ---------------- kernel A: partial sums per (sample, chunk) ----------------
// __launch_bounds__(256, 4): 4 waves/EU min -> VGPR cap 128. We WANT ~96 VGPRs
// so the batched load payloads stay in registers with all loads in flight.
__global__ __launch_bounds__(BLOCK, 4) void score_partial(
    const int*   __restrict__ obj_id,     // [N]
    const float* __restrict__ cam_K,      // [N,3,3]
    const float* __restrict__ gt_R,       // [N,3,3]
    const float* __restrict__ gt_t,       // [N,3]
    const float* __restrict__ pr_R,       // [N,3,3]
    const float* __restrict__ pr_t,       // [N,3]
    const float* __restrict__ coord,      // [N,3,H,W]
    const int*   __restrict__ mask,       // [N,1,H,W]
    const float* __restrict__ mesh,       // [NOBJ,M,3]
    float*       __restrict__ ws,         // [N,SPLIT,4] partials: ad,pj,pv,m
    float*       __restrict__ out)        // [5*N]; this kernel writes re,te
{
    const int b   = blockIdx.x;
    const int n   = b >> 2;               // sample
    const int c   = b & (SPLIT - 1);      // chunk
    const int tid = threadIdx.x;

    // ---- issue ALL phase-2 loads first (16 independent loads in flight) ----
    const float* cx = coord + (size_t)n * 3 * HW;
    const float4* cx4 = (const float4*)cx;
    const float4* cy4 = (const float4*)(cx + HW);
    const float4* cz4 = (const float4*)(cx + 2 * HW);
    const int4*   mk4 = (const int4*)(mask + (size_t)n * HW);

    float4 AX[P2_IT], AY[P2_IT], AZ[P2_IT];
    int4   AM[P2_IT];
#pragma unroll
    for (int it = 0; it < P2_IT; ++it) {
        const int p = c * (HW / 4 / SPLIT) + it * BLOCK + tid;
        AX[it] = cx4[p];
        AY[it] = cy4[p];
        AZ[it] = cz4[p];
        AM[it] = mk4[p];
    }

    // ---- phase-1 mesh loads batched too (6 loads) ----
    const int obj = __builtin_amdgcn_readfirstlane(obj_id[n]);
    const float4* mp4 = (const float4*)(mesh + (size_t)obj * MPTS * 3);
    float4 MF[P1_IT][3];
#pragma unroll
    for (int it = 0; it < P1_IT; ++it) {
        const int k = c * (MPTS / SPLIT / 4) + it * BLOCK + tid;
        MF[it][0] = mp4[k * 3 + 0];
        MF[it][1] = mp4[k * 3 + 1];
        MF[it][2] = mp4[k * 3 + 2];
    }

    // ---- per-sample uniforms (overlaps with loads above) ----
    float K[9], Rg[9], Rp[9], tg[3], tp[3];
#pragma unroll
    for (int i = 0; i < 9; ++i) {
        K[i]  = cam_K[n * 9 + i];
        Rg[i] = gt_R [n * 9 + i];
        Rp[i] = pr_R [n * 9 + i];
    }
#pragma unroll
    for (int i = 0; i < 3; ++i) {
        tg[i] = gt_t[n * 3 + i];
        tp[i] = pr_t[n * 3 + i];
    }

    if (c == 0 && tid == 0) {
        float trace = 0.0f;
#pragma unroll
        for (int i = 0; i < 9; ++i) trace += Rp[i] * Rg[i];
        trace = fminf(fmaxf(trace, -1.0f), 3.0f);
        out[0 * NS + n] = acosf((trace - 1.0f) * 0.5f) * (180.0f / 3.14159265358979323846f);
        const float dx = tp[0] - tg[0], dy = tp[1] - tg[1], dz = tp[2] - tg[2];
        out[1 * NS + n] = sqrtf(dx * dx + dy * dy + dz * dz) * 100.0f;
    }

    // ---- fused constants -> SGPRs ----
    float dR[9], dt[3], Ap[9], Ag[9], bp[3], bg[3];
#pragma unroll
    for (int i = 0; i < 9; ++i) dR[i] = rfl(Rp[i] - Rg[i]);
#pragma unroll
    for (int i = 0; i < 3; ++i) dt[i] = rfl(tp[i] - tg[i]);
#pragma unroll
    for (int r = 0; r < 3; ++r) {
#pragma unroll
        for (int col = 0; col < 3; ++col) {
            Ap[r * 3 + col] = rfl(K[r * 3 + 0] * Rp[0 * 3 + col]
                                + K[r * 3 + 1] * Rp[1 * 3 + col]
                                + K[r * 3 + 2] * Rp[2 * 3 + col]);
            Ag[r * 3 + col] = rfl(K[r * 3 + 0] * Rg[0 * 3 + col]
                                + K[r * 3 + 1] * Rg[1 * 3 + col]
                                + K[r * 3 + 2] * Rg[2 * 3 + col]);
        }
        bp[r] = rfl(K[r * 3 + 0] * tp[0] + K[r * 3 + 1] * tp[1] + K[r * 3 + 2] * tp[2]);
        bg[r] = rfl(K[r * 3 + 0] * tg[0] + K[r * 3 + 1] * tg[1] + K[r * 3 + 2] * tg[2]);
    }

    // ---- phase 1 compute ----
    float s_ad = 0.0f, s_pj = 0.0f;
#pragma unroll
    for (int it = 0; it < P1_IT; ++it) {
        const float4 f0 = MF[it][0], f1 = MF[it][1], f2 = MF[it][2];
        const float px[4] = {f0.x, f0.w, f1.z, f2.y};
        const float py[4] = {f0.y, f1.x, f1.w, f2.z};
        const float pz[4] = {f0.z, f1.y, f2.x, f2.w};
#pragma unroll
        for (int j = 0; j < 4; ++j) {
            const float x = px[j], y = py[j], z = pz[j];
            const float dx = fmaf(dR[0], x, fmaf(dR[1], y, fmaf(dR[2], z, dt[0])));
            const float dy = fmaf(dR[3], x, fmaf(dR[4], y, fmaf(dR[5], z, dt[1])));
            const float dz = fmaf(dR[6], x, fmaf(dR[7], y, fmaf(dR[8], z, dt[2])));
            s_ad += fsqrt(fmaf(dx, dx, fmaf(dy, dy, dz * dz)));
            const float hpx = fmaf(Ap[0], x, fmaf(Ap[1], y, fmaf(Ap[2], z, bp[0])));
            const float hpy = fmaf(Ap[3], x, fmaf(Ap[4], y, fmaf(Ap[5], z, bp[1])));
            const float hpz = fmaf(Ap[6], x, fmaf(Ap[7], y, fmaf(Ap[8], z, bp[2])));
            const float hgx = fmaf(Ag[0], x, fmaf(Ag[1], y, fmaf(Ag[2], z, bg[0])));
            const float hgy = fmaf(Ag[3], x, fmaf(Ag[4], y, fmaf(Ag[5], z, bg[1])));
            const float hgz = fmaf(Ag[6], x, fmaf(Ag[7], y, fmaf(Ag[8], z, bg[2])));
            const float iwp = frcp(hpz), iwg = frcp(hgz);
            const float du = fmaf(hpx, iwp, -hgx * iwg);
            const float dv = fmaf(hpy, iwp, -hgy * iwg);
            s_pj += fsqrt(fmaf(du, du, dv * dv));
        }
    }

    // ---- phase 2 compute (data already in registers) ----
    float s_pv = 0.0f, s_m = 0.0f;
#pragma unroll
    for (int it = 0; it < P2_IT; ++it) {
        const float xs[4] = {AX[it].x, AX[it].y, AX[it].z, AX[it].w};
        const float ys[4] = {AY[it].x, AY[it].y, AY[it].z, AY[it].w};
        const float zs[4] = {AZ[it].x, AZ[it].y, AZ[it].z, AZ[it].w};
        const int   ms[4] = {AM[it].x, AM[it].y, AM[it].z, AM[it].w};
#pragma unroll
        for (int j = 0; j < 4; ++j) {
            const float x = xs[j], y = ys[j], z = zs[j];
            const float hpx = fmaf(Ap[0], x, fmaf(Ap[1], y, fmaf(Ap[2], z, bp[0])));
            const float hpy = fmaf(Ap[3], x, fmaf(Ap[4], y, fmaf(Ap[5], z, bp[1])));
            const float hpz = fmaf(Ap[6], x, fmaf(Ap[7], y, fmaf(Ap[8], z, bp[2])));
            const float hgx = fmaf(Ag[0], x, fmaf(Ag[1], y, fmaf(Ag[2], z, bg[0])));
            const float hgy = fmaf(Ag[3], x, fmaf(Ag[4], y, fmaf(Ag[5], z, bg[1])));
            const float hgz = fmaf(Ag[6], x, fmaf(Ag[7], y, fmaf(Ag[8], z, bg[2])));
            const float iwp = frcp(hpz), iwg = frcp(hgz);
            const float du = fmaf(hpx, iwp, -hgx * iwg);
            const float dv = fmaf(hpy, iwp, -hgy * iwg);
            const float d  = fsqrt(fmaf(du, du, dv * dv));
            const float fm = (ms[j] != 0) ? 1.0f : 0.0f;
            s_pv += d * fm;
            s_m  += fm;
        }
    }

    // ---- block reduction of 4 sums ----
    float vals[4] = {s_ad, s_pj, s_pv, s_m};
#pragma unroll
    for (int k = 0; k < 4; ++k) {
#pragma unroll
        for (int off = 32; off > 0; off >>= 1)
            vals[k] += __shfl_down(vals[k], off, 64);
    }
    __shared__ float red[4][NWAVE];
    const int wave = tid >> 6;
    const int lane = tid & 63;
    if (lane == 0) {
#pragma unroll
        for (int k = 0; k < 4; ++k) red[k][wave] = vals[k];
    }
    __syncthreads();
    if (tid == 0) {
#pragma unroll
        for (int k = 0; k < 4; ++k) {
            float s = 0.0f;
#pragma unroll
            for (int w = 0; w < NWAVE; ++w) s += red[k][w];
            ws[(size_t)(n * SPLIT + c) * 4 + k] = s;
        }
    }
}

// ---------------- kernel B: final reduce over chunks ----------------
__global__ __launch_bounds__(256) void score_reduce(
    const float* __restrict__ ws,        // [N,SPLIT,4]
    const int*   __restrict__ obj_id,    // [N]
    const float* __restrict__ diam,      // [NOBJ]
    float*       __restrict__ out)       // [5*N]
{
    const int n = blockIdx.x * blockDim.x + threadIdx.x;
    if (n >= NS) return;
    float ad = 0.0f, pj = 0.0f, pv = 0.0f, m = 0.0f;
#pragma unroll
    for (int cb = 0; cb < SPLIT; ++cb) {
        const float* p = ws + (size_t)(n * SPLIT + cb) * 4;
        ad += p[0]; pj += p[1]; pv += p[2]; m += p[3];
    }
    const float dia = diam[obj_id[n]];
    out[2 * NS + n] = ad * (1.0f / MPTS) / dia;
    out[3 * NS + n] = pj * (1.0f / MPTS);
    out[4 * NS + n] = pv / fmaxf(m, 1.0f);
}

extern "C" void kernel_launch(void* const* d_in, const int* in_sizes, int n_in,
                              void* d_out, int out_size, void* d_ws, size_t ws_size,
                              hipStream_t stream) {
    const int*   obj_id = (const int*)  d_in[0];
    const float* cam_K  = (const float*)d_in[1];
    const float* gt_R   = (const float*)d_in[2];
    const float* gt_t   = (const float*)d_in[3];
    const float* pr_R   = (const float*)d_in[4];
    const float* pr_t   = (const float*)d_in[5];
    const float* coord  = (const float*)d_in[6];
    const int*   mask   = (const int*)  d_in[7];
    const float* mesh   = (const float*)d_in[8];
    const float* diam   = (const float*)d_in[9];
    float* out = (float*)d_out;
    float* ws  = (float*)d_ws;   // needs N*SPLIT*4*4 = 32 KB

    score_partial<<<NS * SPLIT, BLOCK, 0, stream>>>(obj_id, cam_K, gt_R, gt_t, pr_R,
                                                    pr_t, coord, mask, mesh, ws, out);
    score_reduce<<<(NS + 255) / 256, 256, 0, stream>>>(ws, obj_id, diam, out);
}